// Round 1
// baseline (784.762 us; speedup 1.0000x reference)
//
#include <hip/hip_runtime.h>
#include <hip/hip_bf16.h>

#define DI __device__ __forceinline__

constexpr int N_ = 32, C_ = 64, H_ = 64, W_ = 64;
constexpr int HW = H_ * W_;        // 4096
constexpr int CHW = C_ * HW;       // 262144
constexpr int NELEM = N_ * CHW;    // 8388608

// ---- workspace layout (bytes) ----
constexpr size_t OFF_N1   = 0;                                   // bf16 n1
constexpr size_t OFF_N2   = (size_t)NELEM * 2;                   // bf16 n2
constexpr size_t OFF_W3T  = OFF_N2 + (size_t)NELEM * 2;          // fp32 w3T [3][64ic][9][64oc]
constexpr size_t W3T_PER_EDGE = 64 * 9 * 64;                     // 36864 floats
constexpr size_t OFF_W1T  = OFF_W3T + 3 * W3T_PER_EDGE * 4;      // fp32 w1T [2][64ic][64oc]
constexpr size_t W1T_PER_EDGE = 64 * 64;                         // 4096 floats
constexpr size_t OFF_BIAS = OFF_W1T + 2 * W1T_PER_EDGE * 4;      // fp32 [5][64]
constexpr size_t OFF_CC   = OFF_BIAS + 5 * 64 * 4;               // 2 ints

DI int argmax8(const float* __restrict__ a) {
    int best = 0; float bv = a[0];
#pragma unroll
    for (int i = 1; i < 8; ++i) { float v = a[i]; if (v > bv) { bv = v; best = i; } }
    return best;
}

DI float bf16r(float x) {  // round-trip through bf16 (RNE) to emulate MFMA operand precision
    return __bfloat162float(__float2bfloat16(x));
}

DI float ldin(const float* __restrict__ p, int i) { return p[i]; }
DI float ldin(const __hip_bfloat16* __restrict__ p, int i) { return __bfloat162float(p[i]); }

// ---------------------------------------------------------------------------
// prep: compute c1,c2; fold BN scale + in/out channel masks into bf16-rounded
// transposed weights; fold BN shift into per-edge bias (out-masked).
// bn rows: 0: c3-e0, 1: c3-e1, 2: c1-e0, 3: c3-e2, 4: c1-e1
// ---------------------------------------------------------------------------
__global__ void prep_kernel(const float* __restrict__ w3, const float* __restrict__ w1,
                            const float* __restrict__ bn, const float* __restrict__ a1,
                            const float* __restrict__ a2, char* __restrict__ ws) {
    const int c1 = 8 * (argmax8(a1) + 1);
    const int c2 = 8 * (argmax8(a2) + 1);
    float* __restrict__ w3t  = (float*)(ws + OFF_W3T);
    float* __restrict__ w1t  = (float*)(ws + OFF_W1T);
    float* __restrict__ bias = (float*)(ws + OFF_BIAS);
    int*   __restrict__ cc   = (int*)(ws + OFF_CC);

    const int idx = blockIdx.x * 256 + threadIdx.x;
    if (idx < 3 * 36864) {
        // w3t flat = ((e*64+ic)*9+k)*64+oc
        const int e = idx / 36864, r = idx % 36864;
        const int ic = r / 576, k = (r / 64) % 9, oc = r % 64;
        const int bnrow = (e == 0) ? 0 : (e == 1) ? 1 : 3;
        const float g = bn[(bnrow * 4 + 0) * 64 + oc];
        const float v = bn[(bnrow * 4 + 3) * 64 + oc];
        const float s = g * rsqrtf(v + 1e-5f);
        const float wv = w3[((e * 64 + oc) * 64 + ic) * 9 + k];
        w3t[idx] = (oc < c2 && ic < c1) ? bf16r(wv * s) : 0.f;
    } else if (idx < 3 * 36864 + 2 * 4096) {
        const int j = idx - 3 * 36864;
        const int e = j / 4096, r = j % 4096;
        const int ic = r / 64, oc = r % 64;
        const int bnrow = (e == 0) ? 2 : 4;
        const float g = bn[(bnrow * 4 + 0) * 64 + oc];
        const float v = bn[(bnrow * 4 + 3) * 64 + oc];
        const float s = g * rsqrtf(v + 1e-5f);
        const float wv = w1[(e * 64 + oc) * 64 + ic];
        w1t[j] = (oc < c2 && ic < c1) ? bf16r(wv * s) : 0.f;
    } else if (idx < 3 * 36864 + 2 * 4096 + 320) {
        const int j = idx - (3 * 36864 + 2 * 4096);   // j = bnrow*64 + oc
        const int e = j / 64, oc = j % 64;
        const float g = bn[(e * 4 + 0) * 64 + oc];
        const float b = bn[(e * 4 + 1) * 64 + oc];
        const float m = bn[(e * 4 + 2) * 64 + oc];
        const float v = bn[(e * 4 + 3) * 64 + oc];
        const float s = g * rsqrtf(v + 1e-5f);
        bias[j] = (oc < c2) ? (b - m * s) : 0.f;
    } else if (idx == 3 * 36864 + 2 * 4096 + 320) {
        cc[0] = c1; cc[1] = c2;
    }
}

// ---------------------------------------------------------------------------
// conv3x3: block = 64x * 4y threads, 8 oc per thread (blockIdx.x = oc/8).
// Input rows staged in LDS per 16-ic chunk (relu + bf16-rounded, x padded).
// Weights wave-uniform -> scalar loads. Masks pre-folded into weights/bias.
// ---------------------------------------------------------------------------
template <typename TIN, bool OUT_BF16>
__global__ __launch_bounds__(256) void conv3_kernel(
    const TIN* __restrict__ in,          // [N][64][64][64]
    const float* __restrict__ w3t,       // [64ic][9][64oc], edge pre-offset
    const float* __restrict__ bias,      // [64], edge pre-offset
    const int* __restrict__ cc,
    void* __restrict__ outp) {
    const int c1 = cc[0];
    const int c2 = cc[1];
    const int t = threadIdx.x, x = t & 63, yq = t >> 6;
    const int ocq = blockIdx.x;          // 0..7
    const int y0  = blockIdx.y * 4;
    const int n   = blockIdx.z;
    const int oc0 = ocq * 8;

    __shared__ float sIn[16][6][66];     // [ic-local][row][x+1], 25.3 KB
    float acc[8];
#pragma unroll
    for (int o = 0; o < 8; ++o) acc[o] = 0.f;

    const bool active = (oc0 < c2);

    for (int chunk = 0; chunk < 64; chunk += 16) {
        if (chunk >= c1) break;          // uniform across the whole grid
        // ---- stage 16 ic x 6 rows x 66 cols ----
        for (int idx = t; idx < 16 * 6 * 66; idx += 256) {
            const int icl = idx / 396, rem = idx % 396;
            const int r = rem / 66, xx = rem % 66;
            const int gy = y0 + r - 1, gx = xx - 1;
            float v = 0.f;
            if ((unsigned)gy < 64u && (unsigned)gx < 64u) {
                const float raw = ldin(in, ((n * 64 + (chunk + icl)) * 64 + gy) * 64 + gx);
                v = raw > 0.f ? bf16r(raw) : 0.f;
            }
            sIn[icl][r][xx] = v;
        }
        __syncthreads();
        if (active) {
            for (int icl = 0; icl < 16; ++icl) {
                const float* __restrict__ wrow = w3t + (chunk + icl) * 9 * 64 + oc0;
#pragma unroll
                for (int ky = 0; ky < 3; ++ky) {
                    const float v0 = sIn[icl][yq + ky][x + 0];
                    const float v1 = sIn[icl][yq + ky][x + 1];
                    const float v2 = sIn[icl][yq + ky][x + 2];
#pragma unroll
                    for (int o = 0; o < 8; ++o) {
                        acc[o] += v0 * wrow[(ky * 3 + 0) * 64 + o];
                        acc[o] += v1 * wrow[(ky * 3 + 1) * 64 + o];
                        acc[o] += v2 * wrow[(ky * 3 + 2) * 64 + o];
                    }
                }
            }
        }
        __syncthreads();
    }

    const int y = y0 + yq;
#pragma unroll
    for (int o = 0; o < 8; ++o) {
        const float r = acc[o] + bias[oc0 + o];   // bias/weights already out-masked
        const int oi = ((n * 64 + (oc0 + o)) * 64 + y) * 64 + x;
        if constexpr (OUT_BF16) ((__hip_bfloat16*)outp)[oi] = __float2bfloat16(r);
        else                    ((float*)outp)[oi] = r;
    }
}

// ---------------------------------------------------------------------------
// conv1x1 (accumulating): thread = 1 pixel, all 64 oc in registers.
// FINAL: io is fp32 d_out partial, adds skip (n0). else: io is bf16 n2 partial.
// ---------------------------------------------------------------------------
template <bool FINAL>
__global__ __launch_bounds__(256) void conv1_kernel(
    const __hip_bfloat16* __restrict__ in,  // [N][64][64][64]
    const float* __restrict__ w1t,          // [64ic][64oc], edge pre-offset
    const float* __restrict__ bias,         // [64], edge pre-offset
    const int* __restrict__ cc,
    const float* __restrict__ skip,         // n0 for FINAL, else unused
    void* __restrict__ io) {
    const int c1 = cc[0];
    const int t = threadIdx.x, x = t & 63, yq = t >> 6;
    const int y = blockIdx.x * 4 + yq;
    const int n = blockIdx.y;
    const int base = n * CHW + y * 64 + x;

    float acc[64];
#pragma unroll
    for (int o = 0; o < 64; ++o) acc[o] = 0.f;

    for (int ic = 0; ic < c1; ++ic) {
        float v = __bfloat162float(in[base + ic * HW]);
        v = v > 0.f ? v : 0.f;               // already bf16-precision
        const float* __restrict__ wr = w1t + ic * 64;
#pragma unroll
        for (int o = 0; o < 64; ++o) acc[o] += v * wr[o];
    }

#pragma unroll
    for (int o = 0; o < 64; ++o) {
        const int oi = base + o * HW;
        const float r = acc[o] + bias[o];
        if constexpr (FINAL) {
            float* out = (float*)io;
            out[oi] = out[oi] + r + skip[oi];
        } else {
            __hip_bfloat16* out = (__hip_bfloat16*)io;
            out[oi] = __float2bfloat16(__bfloat162float(out[oi]) + r);
        }
    }
}

// ---------------------------------------------------------------------------
extern "C" void kernel_launch(void* const* d_in, const int* in_sizes, int n_in,
                              void* d_out, int out_size, void* d_ws, size_t ws_size,
                              hipStream_t stream) {
    (void)in_sizes; (void)n_in; (void)out_size; (void)ws_size;
    const float* x  = (const float*)d_in[0];
    const float* a1 = (const float*)d_in[1];
    const float* a2 = (const float*)d_in[2];
    const float* w3 = (const float*)d_in[3];
    const float* w1 = (const float*)d_in[4];
    const float* bn = (const float*)d_in[5];
    char* ws = (char*)d_ws;

    __hip_bfloat16* n1 = (__hip_bfloat16*)(ws + OFF_N1);
    __hip_bfloat16* n2 = (__hip_bfloat16*)(ws + OFF_N2);
    const float* w3t  = (const float*)(ws + OFF_W3T);
    const float* w1t  = (const float*)(ws + OFF_W1T);
    const float* bias = (const float*)(ws + OFF_BIAS);
    const int*   cc   = (const int*)(ws + OFF_CC);

    prep_kernel<<<466, 256, 0, stream>>>(w3, w1, bn, a1, a2, ws);

    const dim3 g3(8, 16, 32);   // ocq, y/4, n
    const dim3 g1(16, 32);      // y/4, n

    // n1 = nor_conv3(n0)                         [bn row 0]
    conv3_kernel<float, true><<<g3, 256, 0, stream>>>(x, w3t + 0 * W3T_PER_EDGE, bias + 0 * 64, cc, n1);
    // n2  = nor_conv3(n0)                        [bn row 1]
    conv3_kernel<float, true><<<g3, 256, 0, stream>>>(x, w3t + 1 * W3T_PER_EDGE, bias + 1 * 64, cc, n2);
    // n2 += nor_conv1(n1)                        [bn row 2]
    conv1_kernel<false><<<g1, 256, 0, stream>>>(n1, w1t + 0 * W1T_PER_EDGE, bias + 2 * 64, cc, nullptr, n2);
    // n3  = nor_conv3(n1)      -> d_out partial  [bn row 3]
    conv3_kernel<__hip_bfloat16, false><<<g3, 256, 0, stream>>>(n1, w3t + 2 * W3T_PER_EDGE, bias + 3 * 64, cc, d_out);
    // n3 += nor_conv1(n2) + n0 -> d_out final    [bn row 4]
    conv1_kernel<true><<<g1, 256, 0, stream>>>(n2, w1t + 1 * W1T_PER_EDGE, bias + 4 * 64, cc, x, d_out);
}

// Round 2
// 607.308 us; speedup vs baseline: 1.2922x; 1.2922x over previous
//
#include <hip/hip_runtime.h>
#include <hip/hip_bf16.h>

#define DI __device__ __forceinline__

typedef __attribute__((ext_vector_type(8))) short bf16x8;   // 8 bf16 = 4 VGPRs (MFMA A/B frag)
typedef __attribute__((ext_vector_type(4))) float f32x4;    // MFMA C/D frag

constexpr int HW = 4096, CHW = 262144;

// ---- workspace layout (bytes), all 16B aligned ----
constexpr size_t OFF_XT   = 0;                       // bf16 NHWC relu(x)      16 MB
constexpr size_t OFF_N1   = 16777216;                // bf16 NHWC relu(n1)     16 MB
constexpr size_t OFF_N2   = 33554432;                // bf16 NHWC relu(n2)     16 MB
constexpr size_t OFF_WB3  = 50331648;                // bf16 [3][9][64oc][64ic]
constexpr size_t OFF_WB1  = OFF_WB3 + 221184;        // bf16 [2][64oc][64ic]
constexpr size_t OFF_BIAS = OFF_WB1 + 16384;         // f32 [5][64]
constexpr size_t OFF_CC   = OFF_BIAS + 1280;         // int[2]

DI int argmax8(const float* __restrict__ a) {
    int best = 0; float bv = a[0];
#pragma unroll
    for (int i = 1; i < 8; ++i) { float v = a[i]; if (v > bv) { bv = v; best = i; } }
    return best;
}

DI short f2bf(float v) {   // fp32 -> bf16 bits (RNE)
    __hip_bfloat16 h = __float2bfloat16(v);
    return __builtin_bit_cast(short, h);
}

// ---------------------------------------------------------------------------
// prep: c1,c2; weights -> bf16 [edge][kpos][oc][ic] with BN scale + channel
// masks folded; per-edge bias (out-masked). bn rows: 0:c3e0 1:c3e1 2:c1e0
// 3:c3e2 4:c1e1
// ---------------------------------------------------------------------------
__global__ void prep_kernel(const float* __restrict__ w3, const float* __restrict__ w1,
                            const float* __restrict__ bn, const float* __restrict__ a1,
                            const float* __restrict__ a2, char* __restrict__ ws) {
    const int c1 = 8 * (argmax8(a1) + 1);
    const int c2 = 8 * (argmax8(a2) + 1);
    short* __restrict__ wb3  = (short*)(ws + OFF_WB3);
    short* __restrict__ wb1  = (short*)(ws + OFF_WB1);
    float* __restrict__ bias = (float*)(ws + OFF_BIAS);
    int*   __restrict__ cc   = (int*)(ws + OFF_CC);

    const int idx = blockIdx.x * 256 + threadIdx.x;
    if (idx < 110592) {                       // wb3 flat = ((e*9+kp)*64+oc)*64+ic
        const int e = idx / 36864, rem = idx % 36864;
        const int kp = rem >> 12, oc = (rem >> 6) & 63, ic = rem & 63;
        const int bnrow = (e == 0) ? 0 : (e == 1) ? 1 : 3;
        const float g = bn[(bnrow * 4 + 0) * 64 + oc];
        const float v = bn[(bnrow * 4 + 3) * 64 + oc];
        const float s = g * rsqrtf(v + 1e-5f);
        const float wv = w3[((e * 64 + oc) * 64 + ic) * 9 + kp];
        wb3[idx] = (oc < c2 && ic < c1) ? f2bf(wv * s) : (short)0;
    } else if (idx < 118784) {                // wb1 flat = (e*64+oc)*64+ic
        const int j = idx - 110592;
        const int e = j >> 12, oc = (j >> 6) & 63, ic = j & 63;
        const int bnrow = (e == 0) ? 2 : 4;
        const float g = bn[(bnrow * 4 + 0) * 64 + oc];
        const float v = bn[(bnrow * 4 + 3) * 64 + oc];
        const float s = g * rsqrtf(v + 1e-5f);
        wb1[j] = (oc < c2 && ic < c1) ? f2bf(w1[(e * 64 + oc) * 64 + ic] * s) : (short)0;
    } else if (idx < 119104) {                // bias
        const int j = idx - 118784;
        const int e = j >> 6, oc = j & 63;
        const float g = bn[(e * 4 + 0) * 64 + oc];
        const float b = bn[(e * 4 + 1) * 64 + oc];
        const float m = bn[(e * 4 + 2) * 64 + oc];
        const float v = bn[(e * 4 + 3) * 64 + oc];
        bias[j] = (oc < c2) ? (b - m * g * rsqrtf(v + 1e-5f)) : 0.f;
    } else if (idx == 119104) {
        cc[0] = c1; cc[1] = c2;
    }
}

// ---------------------------------------------------------------------------
// transform: x fp32 NCHW -> relu(x) bf16 NHWC, LDS-transposed for coalescing.
// block = (n, y) tile: 64 c x 64 x.
// ---------------------------------------------------------------------------
__global__ __launch_bounds__(256) void transform_kernel(const float* __restrict__ x,
                                                        short* __restrict__ xT) {
    __shared__ short sT[64 * 72];             // [x][c], 72-pad
    const int t = threadIdx.x, y = blockIdx.x, n = blockIdx.y;
    const int xc = t & 63, c0 = t >> 6;
    const float* __restrict__ src = x + (size_t)(n * 64) * HW + y * 64;
#pragma unroll
    for (int p = 0; p < 16; ++p) {
        const int c = p * 4 + c0;
        sT[xc * 72 + c] = f2bf(fmaxf(src[c * HW + xc], 0.f));
    }
    __syncthreads();
    short* __restrict__ dst = xT + (size_t)((n * 64 + y) * 64) * 64;
    const int cs = t & 7, xr = t >> 3;
#pragma unroll
    for (int p = 0; p < 2; ++p) {
        const int xx = p * 32 + xr;
        *(bf16x8*)(dst + xx * 64 + cs * 8) = *(const bf16x8*)(&sT[xx * 72 + cs * 8]);
    }
}

// ---------------------------------------------------------------------------
// MFMA implicit-GEMM conv. Block = 4 waves; wave w -> output row y0+w,
// 64 pixels x 64 oc (4x4 tiles of 16x16x32 MFMA). Stage1 = conv3x3 (9 shifted
// GEMMs) over A1; optional stage2 = conv1x1 over A2 (restaged into sA center).
// A-frag: A[m=lane&15][k=quad*8+j]; B-frag: B[n=lane&15][k=quad*8+j];
// D: col(oc)=lane&15, row(pix)=quad*4+reg.
// ---------------------------------------------------------------------------
template <bool TWO, bool FINAL>
__global__ __launch_bounds__(256, 2) void conv_kernel(
    const short* __restrict__ A1,      // bf16 NHWC (already relu'd)
    const short* __restrict__ A2,      // bf16 NHWC (already relu'd) or null
    const short* __restrict__ WB1k,    // bf16 [9][64][64] stage1 weights
    const short* __restrict__ WB2k,    // bf16 [64][64] stage2 weights or null
    const float* __restrict__ bias1,
    const float* __restrict__ bias2,
    const int* __restrict__ cc,
    const float* __restrict__ skip,    // FINAL: raw x fp32 NCHW
    void* __restrict__ outp) {         // FINAL: f32 NCHW else bf16 NHWC
    constexpr int SAS = 72;            // sA/sB ic-stride (36 dwords: bank-balanced)
    __shared__ __align__(16) short sA[6 * 66 * SAS];   // 57.0 KB
    __shared__ __align__(16) short sB[2 * 64 * SAS];   // 18.4 KB

    const int t = threadIdx.x, w = t >> 6, l = t & 63, lm = l & 15, q = l >> 4;
    const int y0 = blockIdx.x * 4, n = blockIdx.y;
    const int c1 = cc[0], c2 = cc[1];
    const int kcM = (c1 > 32) ? 2 : 1;         // K-chunks of 32 ic
    const int ntL = (c2 + 15) >> 4;            // live oc tiles
    const int SGm = kcM * 4;                   // live 8-ic segments

    f32x4 acc[4][4];
#pragma unroll
    for (int i = 0; i < 4; ++i)
#pragma unroll
        for (int j = 0; j < 4; ++j) acc[i][j] = 0.f;

    // ---- stage sA: 6 rows (y0-1..y0+4) x 66 cols (halo) x live ic ----
    for (int idx = t; idx < 6 * 66 * 8; idx += 256) {
        const int r = idx / 528, rem = idx - r * 528, c = rem >> 3, sg = rem & 7;
        if (sg < SGm) {
            const int gy = y0 + r - 1, gx = c - 1;
            bf16x8 v = 0;
            if ((unsigned)gy < 64u && (unsigned)gx < 64u)
                v = *(const bf16x8*)(A1 + ((n * 64 + gy) * 64 + gx) * 64 + sg * 8);
            *(bf16x8*)(&sA[(r * 66 + c) * SAS + sg * 8]) = v;
        }
    }

    auto stageB = [&](int buf, const short* __restrict__ Wsrc) {
#pragma unroll
        for (int i = 0; i < 2; ++i) {
            const int j = t + i * 256;
            const int oc = j >> 3, sg = j & 7;
            *(bf16x8*)(&sB[(buf * 64 + oc) * SAS + sg * 8]) =
                *(const bf16x8*)(Wsrc + oc * 64 + sg * 8);
        }
    };

    auto compute = [&](int buf, int ky, int kx) {
        for (int kc = 0; kc < kcM; ++kc) {
            bf16x8 af[4], bfr[4];
#pragma unroll
            for (int mt = 0; mt < 4; ++mt)
                af[mt] = *(const bf16x8*)(&sA[((w + ky) * 66 + (mt * 16 + lm + kx)) * SAS + kc * 32 + q * 8]);
            for (int nt = 0; nt < ntL; ++nt)
                bfr[nt] = *(const bf16x8*)(&sB[(buf * 64 + nt * 16 + lm) * SAS + kc * 32 + q * 8]);
            for (int nt = 0; nt < ntL; ++nt)
#pragma unroll
                for (int mt = 0; mt < 4; ++mt)
                    acc[mt][nt] = __builtin_amdgcn_mfma_f32_16x16x32_bf16(
                        af[mt], bfr[nt], acc[mt][nt], 0, 0, 0);
        }
    };

    stageB(0, WB1k);
    __syncthreads();

    for (int kp = 0; kp < 9; ++kp) {
        const int buf = kp & 1;
        if (kp < 8)       stageB(buf ^ 1, WB1k + (kp + 1) * 4096);   // prefetch next kpos
        else if (TWO)     stageB(buf ^ 1, WB2k);                     // prefetch stage2
        compute(buf, kp / 3, kp % 3);
        __syncthreads();   // guards sB double-buffer + (last iter) sA restage
    }

    if (TWO) {
        // restage sA center (rows 1..4, cols 1..64) with stage2 input
        for (int idx = t; idx < 4 * 64 * 8; idx += 256) {
            const int r = idx >> 9, rem = idx & 511, c = rem >> 3, sg = rem & 7;
            if (sg < SGm) {
                *(bf16x8*)(&sA[((r + 1) * 66 + (c + 1)) * SAS + sg * 8]) =
                    *(const bf16x8*)(A2 + ((n * 64 + y0 + r) * 64 + c) * 64 + sg * 8);
            }
        }
        __syncthreads();
        compute(1, 1, 1);   // sB buf1 holds stage2 weights (staged at kp=8)
    }

    // ---- epilogue ----
    const int y = y0 + w;
#pragma unroll
    for (int nt = 0; nt < 4; ++nt) {
        const int oc = nt * 16 + lm;
        float bb = bias1[oc];
        if (TWO) bb += bias2[oc];
#pragma unroll
        for (int mt = 0; mt < 4; ++mt) {
#pragma unroll
            for (int r = 0; r < 4; ++r) {
                const int xp = mt * 16 + q * 4 + r;
                const float vv = acc[mt][nt][r] + bb;   // oc>=c2: acc=0,bias=0 -> 0
                if constexpr (FINAL) {
                    const int oi = ((n * 64 + oc) * 64 + y) * 64 + xp;
                    ((float*)outp)[oi] = vv + skip[oi];
                } else {
                    ((short*)outp)[((n * 64 + y) * 64 + xp) * 64 + oc] = f2bf(fmaxf(vv, 0.f));
                }
            }
        }
    }
}

// ---------------------------------------------------------------------------
extern "C" void kernel_launch(void* const* d_in, const int* in_sizes, int n_in,
                              void* d_out, int out_size, void* d_ws, size_t ws_size,
                              hipStream_t stream) {
    (void)in_sizes; (void)n_in; (void)out_size; (void)ws_size;
    const float* x  = (const float*)d_in[0];
    const float* a1 = (const float*)d_in[1];
    const float* a2 = (const float*)d_in[2];
    const float* w3 = (const float*)d_in[3];
    const float* w1 = (const float*)d_in[4];
    const float* bn = (const float*)d_in[5];
    char* ws = (char*)d_ws;

    short* xT = (short*)(ws + OFF_XT);
    short* n1 = (short*)(ws + OFF_N1);
    short* n2 = (short*)(ws + OFF_N2);
    const short* wb3  = (const short*)(ws + OFF_WB3);
    const short* wb1  = (const short*)(ws + OFF_WB1);
    const float* bias = (const float*)(ws + OFF_BIAS);
    const int*   cc   = (const int*)(ws + OFF_CC);

    prep_kernel<<<466, 256, 0, stream>>>(w3, w1, bn, a1, a2, ws);
    transform_kernel<<<dim3(64, 32), 256, 0, stream>>>(x, xT);

    const dim3 gc(16, 32);   // y-tiles, n
    // n1 = relu(conv3(x~) e0)
    conv_kernel<false, false><<<gc, 256, 0, stream>>>(
        xT, nullptr, wb3, nullptr, bias, nullptr, cc, nullptr, n1);
    // n2 = relu(conv3(x~) e1 + conv1(n1~) e0)
    conv_kernel<true, false><<<gc, 256, 0, stream>>>(
        xT, n1, wb3 + 36864, wb1, bias + 64, bias + 128, cc, nullptr, n2);
    // d_out = x + conv3(n1~) e2 + conv1(n2~) e1
    conv_kernel<true, true><<<gc, 256, 0, stream>>>(
        n1, n2, wb3 + 2 * 36864, wb1 + 4096, bias + 192, bias + 256, cc, x, d_out);
}

// Round 3
// 150.851 us; speedup vs baseline: 5.2022x; 4.0259x over previous
//
#include <hip/hip_runtime.h>
#include <hip/hip_bf16.h>

#define DI __device__ __forceinline__

typedef __attribute__((ext_vector_type(8))) short bf16x8;   // 8 bf16 = 4 VGPRs (MFMA A/B frag)
typedef __attribute__((ext_vector_type(4))) float f32x4;    // MFMA C/D frag

constexpr int HW = 4096, CHW = 262144;

// ---- workspace layout (bytes), all 16B aligned ----
constexpr size_t OFF_XT   = 0;                       // bf16 NHWC relu(x)      16 MB
constexpr size_t OFF_N1   = 16777216;                // bf16 NHWC relu(n1)     16 MB
constexpr size_t OFF_N2   = 33554432;                // bf16 NHWC relu(n2)     16 MB
constexpr size_t OFF_WB3  = 50331648;                // bf16 [3][9][64oc][64ic]
constexpr size_t OFF_WB1  = OFF_WB3 + 221184;        // bf16 [2][64oc][64ic]
constexpr size_t OFF_BIAS = OFF_WB1 + 16384;         // f32 [5][64]
constexpr size_t OFF_CC   = OFF_BIAS + 1280;         // int[2]

DI int argmax8(const float* __restrict__ a) {
    int best = 0; float bv = a[0];
#pragma unroll
    for (int i = 1; i < 8; ++i) { float v = a[i]; if (v > bv) { bv = v; best = i; } }
    return best;
}

DI short f2bf(float v) {   // fp32 -> bf16 bits (RNE)
    __hip_bfloat16 h = __float2bfloat16(v);
    return __builtin_bit_cast(short, h);
}

// ---------------------------------------------------------------------------
// prep: c1,c2; weights -> bf16 [edge][kpos][oc][ic] with BN scale + channel
// masks folded; per-edge bias (out-masked). bn rows: 0:c3e0 1:c3e1 2:c1e0
// 3:c3e2 4:c1e1
// ---------------------------------------------------------------------------
__global__ void prep_kernel(const float* __restrict__ w3, const float* __restrict__ w1,
                            const float* __restrict__ bn, const float* __restrict__ a1,
                            const float* __restrict__ a2, char* __restrict__ ws) {
    const int c1 = 8 * (argmax8(a1) + 1);
    const int c2 = 8 * (argmax8(a2) + 1);
    short* __restrict__ wb3  = (short*)(ws + OFF_WB3);
    short* __restrict__ wb1  = (short*)(ws + OFF_WB1);
    float* __restrict__ bias = (float*)(ws + OFF_BIAS);
    int*   __restrict__ cc   = (int*)(ws + OFF_CC);

    const int idx = blockIdx.x * 256 + threadIdx.x;
    if (idx < 110592) {                       // wb3 flat = ((e*9+kp)*64+oc)*64+ic
        const int e = idx / 36864, rem = idx % 36864;
        const int kp = rem >> 12, oc = (rem >> 6) & 63, ic = rem & 63;
        const int bnrow = (e == 0) ? 0 : (e == 1) ? 1 : 3;
        const float g = bn[(bnrow * 4 + 0) * 64 + oc];
        const float v = bn[(bnrow * 4 + 3) * 64 + oc];
        const float s = g * rsqrtf(v + 1e-5f);
        const float wv = w3[((e * 64 + oc) * 64 + ic) * 9 + kp];
        wb3[idx] = (oc < c2 && ic < c1) ? f2bf(wv * s) : (short)0;
    } else if (idx < 118784) {                // wb1 flat = (e*64+oc)*64+ic
        const int j = idx - 110592;
        const int e = j >> 12, oc = (j >> 6) & 63, ic = j & 63;
        const int bnrow = (e == 0) ? 2 : 4;
        const float g = bn[(bnrow * 4 + 0) * 64 + oc];
        const float v = bn[(bnrow * 4 + 3) * 64 + oc];
        const float s = g * rsqrtf(v + 1e-5f);
        wb1[j] = (oc < c2 && ic < c1) ? f2bf(w1[(e * 64 + oc) * 64 + ic] * s) : (short)0;
    } else if (idx < 119104) {                // bias
        const int j = idx - 118784;
        const int e = j >> 6, oc = j & 63;
        const float g = bn[(e * 4 + 0) * 64 + oc];
        const float b = bn[(e * 4 + 1) * 64 + oc];
        const float m = bn[(e * 4 + 2) * 64 + oc];
        const float v = bn[(e * 4 + 3) * 64 + oc];
        bias[j] = (oc < c2) ? (b - m * g * rsqrtf(v + 1e-5f)) : 0.f;
    } else if (idx == 119104) {
        cc[0] = c1; cc[1] = c2;
    }
}

// ---------------------------------------------------------------------------
// transform: x fp32 NCHW -> relu(x) bf16 NHWC, LDS-transposed for coalescing.
// block = (n, y) tile: 64 c x 64 x.
// ---------------------------------------------------------------------------
__global__ __launch_bounds__(256) void transform_kernel(const float* __restrict__ x,
                                                        short* __restrict__ xT) {
    __shared__ short sT[64 * 72];             // [x][c], 72-pad
    const int t = threadIdx.x, y = blockIdx.x, n = blockIdx.y;
    const int xc = t & 63, c0 = t >> 6;
    const float* __restrict__ src = x + (size_t)(n * 64) * HW + y * 64;
#pragma unroll
    for (int p = 0; p < 16; ++p) {
        const int c = p * 4 + c0;
        sT[xc * 72 + c] = f2bf(fmaxf(src[c * HW + xc], 0.f));
    }
    __syncthreads();
    short* __restrict__ dst = xT + (size_t)((n * 64 + y) * 64) * 64;
    const int cs = t & 7, xr = t >> 3;
#pragma unroll
    for (int p = 0; p < 2; ++p) {
        const int xx = p * 32 + xr;
        *(bf16x8*)(dst + xx * 64 + cs * 8) = *(const bf16x8*)(&sT[xx * 72 + cs * 8]);
    }
}

// ---------------------------------------------------------------------------
// MFMA implicit-GEMM conv. Block = 4 waves; wave w -> output row y0+w,
// 64 pixels x 64 oc (4x4 tiles of 16x16x32 MFMA). Stage1 = conv3x3 (9 shifted
// GEMMs) over A1; optional stage2 = conv1x1 over A2 (restaged into sA center).
// ALL register-array loops are compile-time (acc/af/bfr must stay in VGPRs —
// round-2 lesson: runtime trip counts spilled acc to scratch, 160x slowdown).
// Channel culling is wave-uniform scalar guards around unrolled bodies.
// ---------------------------------------------------------------------------
template <bool TWO, bool FINAL>
__global__ __launch_bounds__(256, 2) void conv_kernel(
    const short* __restrict__ A1,      // bf16 NHWC (already relu'd)
    const short* __restrict__ A2,      // bf16 NHWC (already relu'd) or null
    const short* __restrict__ WB1k,    // bf16 [9][64][64] stage1 weights
    const short* __restrict__ WB2k,    // bf16 [64][64] stage2 weights or null
    const float* __restrict__ bias1,
    const float* __restrict__ bias2,
    const int* __restrict__ cc,
    const float* __restrict__ skip,    // FINAL: raw x fp32 NCHW
    void* __restrict__ outp) {         // FINAL: f32 NCHW else bf16 NHWC
    constexpr int SAS = 72;            // sA/sB ic-stride (36 dwords: bank-balanced)
    __shared__ __align__(16) short sA[6 * 66 * SAS];   // 57.0 KB
    __shared__ __align__(16) short sB[2 * 64 * SAS];   // 18.4 KB

    const int t = threadIdx.x, w = t >> 6, l = t & 63, lm = l & 15, q = l >> 4;
    const int y0 = blockIdx.x * 4, n = blockIdx.y;
    const int c1 = __builtin_amdgcn_readfirstlane(cc[0]);
    const int c2 = __builtin_amdgcn_readfirstlane(cc[1]);
    const int SGm = (c1 > 32) ? 8 : 4;         // live 8-ic staging segments

    f32x4 acc[4][4];
#pragma unroll
    for (int i = 0; i < 4; ++i)
#pragma unroll
        for (int j = 0; j < 4; ++j) acc[i][j] = 0.f;

    // ---- stage sA: 6 rows (y0-1..y0+4) x 66 cols (halo) x live ic ----
    for (int idx = t; idx < 6 * 66 * 8; idx += 256) {
        const int r = idx / 528, rem = idx - r * 528, c = rem >> 3, sg = rem & 7;
        if (sg < SGm) {
            const int gy = y0 + r - 1, gx = c - 1;
            bf16x8 v = 0;
            if ((unsigned)gy < 64u && (unsigned)gx < 64u)
                v = *(const bf16x8*)(A1 + ((n * 64 + gy) * 64 + gx) * 64 + sg * 8);
            *(bf16x8*)(&sA[(r * 66 + c) * SAS + sg * 8]) = v;
        }
    }

    auto stageB = [&](int buf, const short* __restrict__ Wsrc) {
#pragma unroll
        for (int i = 0; i < 2; ++i) {
            const int j = t + i * 256;
            const int oc = j >> 3, sg = j & 7;
            *(bf16x8*)(&sB[(buf * 64 + oc) * SAS + sg * 8]) =
                *(const bf16x8*)(Wsrc + oc * 64 + sg * 8);
        }
    };

    auto compute = [&](int buf, int ky, int kx) {
#pragma unroll
        for (int kc = 0; kc < 2; ++kc) {
            if (kc == 0 || c1 > 32) {          // wave-uniform K-chunk cull
                bf16x8 af[4], bfr[4];
#pragma unroll
                for (int mt = 0; mt < 4; ++mt)
                    af[mt] = *(const bf16x8*)(&sA[((w + ky) * 66 + (mt * 16 + lm + kx)) * SAS + kc * 32 + q * 8]);
#pragma unroll
                for (int nt = 0; nt < 4; ++nt) {
                    if (nt * 16 < c2) {        // wave-uniform oc-tile cull
                        bfr[nt] = *(const bf16x8*)(&sB[(buf * 64 + nt * 16 + lm) * SAS + kc * 32 + q * 8]);
#pragma unroll
                        for (int mt = 0; mt < 4; ++mt)
                            acc[mt][nt] = __builtin_amdgcn_mfma_f32_16x16x32_bf16(
                                af[mt], bfr[nt], acc[mt][nt], 0, 0, 0);
                    }
                }
            }
        }
    };

    stageB(0, WB1k);
    __syncthreads();

    for (int kp = 0; kp < 9; ++kp) {
        const int buf = kp & 1;
        if (kp < 8)       stageB(buf ^ 1, WB1k + (kp + 1) * 4096);   // prefetch next kpos
        else if (TWO)     stageB(buf ^ 1, WB2k);                     // prefetch stage2
        compute(buf, kp / 3, kp % 3);
        __syncthreads();   // guards sB double-buffer + (last iter) sA restage
    }

    if (TWO) {
        // restage sA center (rows 1..4, cols 1..64) with stage2 input
        for (int idx = t; idx < 4 * 64 * 8; idx += 256) {
            const int r = idx >> 9, rem = idx & 511, c = rem >> 3, sg = rem & 7;
            if (sg < SGm) {
                *(bf16x8*)(&sA[((r + 1) * 66 + (c + 1)) * SAS + sg * 8]) =
                    *(const bf16x8*)(A2 + ((n * 64 + y0 + r) * 64 + c) * 64 + sg * 8);
            }
        }
        __syncthreads();
        compute(1, 1, 1);   // sB buf1 holds stage2 weights (staged at kp=8)
    }

    // ---- epilogue ----
    const int y = y0 + w;
#pragma unroll
    for (int nt = 0; nt < 4; ++nt) {
        const int oc = nt * 16 + lm;
        float bb = bias1[oc];
        if (TWO) bb += bias2[oc];
#pragma unroll
        for (int mt = 0; mt < 4; ++mt) {
#pragma unroll
            for (int r = 0; r < 4; ++r) {
                const int xp = mt * 16 + q * 4 + r;
                const float vv = acc[mt][nt][r] + bb;   // oc>=c2: acc=0,bias=0 -> 0
                if constexpr (FINAL) {
                    const int oi = ((n * 64 + oc) * 64 + y) * 64 + xp;
                    ((float*)outp)[oi] = vv + skip[oi];
                } else {
                    ((short*)outp)[((n * 64 + y) * 64 + xp) * 64 + oc] = f2bf(fmaxf(vv, 0.f));
                }
            }
        }
    }
}

// ---------------------------------------------------------------------------
extern "C" void kernel_launch(void* const* d_in, const int* in_sizes, int n_in,
                              void* d_out, int out_size, void* d_ws, size_t ws_size,
                              hipStream_t stream) {
    (void)in_sizes; (void)n_in; (void)out_size; (void)ws_size;
    const float* x  = (const float*)d_in[0];
    const float* a1 = (const float*)d_in[1];
    const float* a2 = (const float*)d_in[2];
    const float* w3 = (const float*)d_in[3];
    const float* w1 = (const float*)d_in[4];
    const float* bn = (const float*)d_in[5];
    char* ws = (char*)d_ws;

    short* xT = (short*)(ws + OFF_XT);
    short* n1 = (short*)(ws + OFF_N1);
    short* n2 = (short*)(ws + OFF_N2);
    const short* wb3  = (const short*)(ws + OFF_WB3);
    const short* wb1  = (const short*)(ws + OFF_WB1);
    const float* bias = (const float*)(ws + OFF_BIAS);
    const int*   cc   = (const int*)(ws + OFF_CC);

    prep_kernel<<<466, 256, 0, stream>>>(w3, w1, bn, a1, a2, ws);
    transform_kernel<<<dim3(64, 32), 256, 0, stream>>>(x, xT);

    const dim3 gc(16, 32);   // y-tiles, n
    // n1 = relu(conv3(x~) e0)
    conv_kernel<false, false><<<gc, 256, 0, stream>>>(
        xT, nullptr, wb3, nullptr, bias, nullptr, cc, nullptr, n1);
    // n2 = relu(conv3(x~) e1 + conv1(n1~) e0)
    conv_kernel<true, false><<<gc, 256, 0, stream>>>(
        xT, n1, wb3 + 36864, wb1, bias + 64, bias + 128, cc, nullptr, n2);
    // d_out = x + conv3(n1~) e2 + conv1(n2~) e1
    conv_kernel<true, true><<<gc, 256, 0, stream>>>(
        n1, n2, wb3 + 2 * 36864, wb1 + 4096, bias + 192, bias + 256, cc, x, d_out);
}

// Round 4
// 148.913 us; speedup vs baseline: 5.2699x; 1.0130x over previous
//
#include <hip/hip_runtime.h>
#include <hip/hip_bf16.h>

#define DI __device__ __forceinline__

typedef __attribute__((ext_vector_type(8))) short bf16x8;   // 8 bf16 = 4 VGPRs (MFMA A/B frag)
typedef __attribute__((ext_vector_type(4))) float f32x4;    // MFMA C/D frag

constexpr int HW = 4096, CHW = 262144;

// ---- workspace layout (bytes), all 16B aligned ----
constexpr size_t OFF_XT   = 0;                       // bf16 NHWC relu(x)      16 MB
constexpr size_t OFF_N1   = 16777216;                // bf16 NHWC relu(n1)     16 MB
constexpr size_t OFF_N2   = 33554432;                // bf16 NHWC relu(n2)     16 MB
constexpr size_t OFF_WB3  = 50331648;                // bf16 [3][9][64oc][64ic]  (frag order)
constexpr size_t OFF_WB1  = OFF_WB3 + 221184;        // bf16 [2][64oc][64ic]
constexpr size_t OFF_BIAS = OFF_WB1 + 16384;         // f32 [5][64]
constexpr size_t OFF_CC   = OFF_BIAS + 1280;         // int[2]

DI int argmax8(const float* __restrict__ a) {
    int best = 0; float bv = a[0];
#pragma unroll
    for (int i = 1; i < 8; ++i) { float v = a[i]; if (v > bv) { bv = v; best = i; } }
    return best;
}

DI short f2bf(float v) {   // fp32 -> bf16 bits (RNE)
    __hip_bfloat16 h = __float2bfloat16(v);
    return __builtin_bit_cast(short, h);
}

// ---------------------------------------------------------------------------
// prep: c1,c2; weights -> bf16 [edge][kpos][oc][ic] with BN scale + channel
// masks folded; per-edge bias (out-masked). bn rows: 0:c3e0 1:c3e1 2:c1e0
// 3:c3e2 4:c1e1
// ---------------------------------------------------------------------------
__global__ void prep_kernel(const float* __restrict__ w3, const float* __restrict__ w1,
                            const float* __restrict__ bn, const float* __restrict__ a1,
                            const float* __restrict__ a2, char* __restrict__ ws) {
    const int c1 = 8 * (argmax8(a1) + 1);
    const int c2 = 8 * (argmax8(a2) + 1);
    short* __restrict__ wb3  = (short*)(ws + OFF_WB3);
    short* __restrict__ wb1  = (short*)(ws + OFF_WB1);
    float* __restrict__ bias = (float*)(ws + OFF_BIAS);
    int*   __restrict__ cc   = (int*)(ws + OFF_CC);

    const int idx = blockIdx.x * 256 + threadIdx.x;
    if (idx < 110592) {                       // wb3 flat = ((e*9+kp)*64+oc)*64+ic
        const int e = idx / 36864, rem = idx % 36864;
        const int kp = rem >> 12, oc = (rem >> 6) & 63, ic = rem & 63;
        const int bnrow = (e == 0) ? 0 : (e == 1) ? 1 : 3;
        const float g = bn[(bnrow * 4 + 0) * 64 + oc];
        const float v = bn[(bnrow * 4 + 3) * 64 + oc];
        const float s = g * rsqrtf(v + 1e-5f);
        const float wv = w3[((e * 64 + oc) * 64 + ic) * 9 + kp];
        wb3[idx] = (oc < c2 && ic < c1) ? f2bf(wv * s) : (short)0;
    } else if (idx < 118784) {                // wb1 flat = (e*64+oc)*64+ic
        const int j = idx - 110592;
        const int e = j >> 12, oc = (j >> 6) & 63, ic = j & 63;
        const int bnrow = (e == 0) ? 2 : 4;
        const float g = bn[(bnrow * 4 + 0) * 64 + oc];
        const float v = bn[(bnrow * 4 + 3) * 64 + oc];
        const float s = g * rsqrtf(v + 1e-5f);
        wb1[j] = (oc < c2 && ic < c1) ? f2bf(w1[(e * 64 + oc) * 64 + ic] * s) : (short)0;
    } else if (idx < 119104) {                // bias
        const int j = idx - 118784;
        const int e = j >> 6, oc = j & 63;
        const float g = bn[(e * 4 + 0) * 64 + oc];
        const float b = bn[(e * 4 + 1) * 64 + oc];
        const float m = bn[(e * 4 + 2) * 64 + oc];
        const float v = bn[(e * 4 + 3) * 64 + oc];
        bias[j] = (oc < c2) ? (b - m * g * rsqrtf(v + 1e-5f)) : 0.f;
    } else if (idx == 119104) {
        cc[0] = c1; cc[1] = c2;
    }
}

// ---------------------------------------------------------------------------
// transform: x fp32 NCHW -> relu(x) bf16 NHWC, LDS-transposed for coalescing.
// block = (n, y) tile: 64 c x 64 x.
// ---------------------------------------------------------------------------
__global__ __launch_bounds__(256) void transform_kernel(const float* __restrict__ x,
                                                        short* __restrict__ xT) {
    __shared__ short sT[64 * 72];             // [x][c], 72-pad
    const int t = threadIdx.x, y = blockIdx.x, n = blockIdx.y;
    const int xc = t & 63, c0 = t >> 6;
    const float* __restrict__ src = x + (size_t)(n * 64) * HW + y * 64;
#pragma unroll
    for (int p = 0; p < 16; ++p) {
        const int c = p * 4 + c0;
        sT[xc * 72 + c] = f2bf(fmaxf(src[c * HW + xc], 0.f));
    }
    __syncthreads();
    short* __restrict__ dst = xT + (size_t)((n * 64 + y) * 64) * 64;
    const int cs = t & 7, xr = t >> 3;
#pragma unroll
    for (int p = 0; p < 2; ++p) {
        const int xx = p * 32 + xr;
        *(bf16x8*)(dst + xx * 64 + cs * 8) = *(const bf16x8*)(&sT[xx * 72 + cs * 8]);
    }
}

// ---------------------------------------------------------------------------
// MFMA implicit-GEMM conv, BARRIER-FREE K-loop. Block = 4 waves; wave w ->
// output row y0+w, 64 pix x 64 oc (4x4 tiles of 16x16x32 MFMA).
// A staged once in LDS (read-only during the 9-kpos loop -> no barriers);
// B-fragments loaded straight from global per kpos (wb3 is in exact frag
// order; 4 KB/kpos, L2-hot across all 512 blocks). Round-2 lesson: every
// register-array index compile-time; channel culls are wave-uniform guards.
// ---------------------------------------------------------------------------
template <bool TWO, bool FINAL>
__global__ __launch_bounds__(256, 2) void conv_kernel(
    const short* __restrict__ A1,      // bf16 NHWC (already relu'd)
    const short* __restrict__ A2,      // bf16 NHWC (already relu'd) or null
    const short* __restrict__ WB1k,    // bf16 [9][64][64] stage1 weights (frag order)
    const short* __restrict__ WB2k,    // bf16 [64][64] stage2 weights or null
    const float* __restrict__ bias1,
    const float* __restrict__ bias2,
    const int* __restrict__ cc,
    const float* __restrict__ skip,    // FINAL: raw x fp32 NCHW
    void* __restrict__ outp) {         // FINAL: f32 NCHW else bf16 NHWC
    constexpr int SAS = 72;            // sA ic-stride: 36 dwords -> conflict-free b128
    __shared__ __align__(16) short sA[6 * 66 * SAS];   // 55.7 KB, sole LDS use

    const int t = threadIdx.x, w = t >> 6, l = t & 63, lm = l & 15, q = l >> 4;
    const int y0 = blockIdx.x * 4, n = blockIdx.y;
    const int c1 = __builtin_amdgcn_readfirstlane(cc[0]);
    const int c2 = __builtin_amdgcn_readfirstlane(cc[1]);
    const int SGm = (c1 > 32) ? 8 : 4;         // live 8-ic staging segments

    f32x4 acc[4][4];
#pragma unroll
    for (int i = 0; i < 4; ++i)
#pragma unroll
        for (int j = 0; j < 4; ++j) acc[i][j] = 0.f;

    // ---- stage sA: 6 rows (y0-1..y0+4) x 66 cols (halo) x live ic ----
    for (int idx = t; idx < 6 * 66 * 8; idx += 256) {
        const int r = idx / 528, rem = idx - r * 528, c = rem >> 3, sg = rem & 7;
        if (sg < SGm) {
            const int gy = y0 + r - 1, gx = c - 1;
            bf16x8 v = 0;
            if ((unsigned)gy < 64u && (unsigned)gx < 64u)
                v = *(const bf16x8*)(A1 + ((n * 64 + gy) * 64 + gx) * 64 + sg * 8);
            *(bf16x8*)(&sA[(r * 66 + c) * SAS + sg * 8]) = v;
        }
    }

    // Wk points at this kpos's [64oc][64ic] block; lane frag = contiguous 16B.
    auto compute = [&](const short* __restrict__ Wk, int ky, int kx) {
#pragma unroll
        for (int kc = 0; kc < 2; ++kc) {
            if (kc == 0 || c1 > 32) {          // wave-uniform K-chunk cull
                bf16x8 af[4], bfr[4];
#pragma unroll
                for (int nt = 0; nt < 4; ++nt)
                    if (nt * 16 < c2)          // wave-uniform oc-tile cull
                        bfr[nt] = *(const bf16x8*)(Wk + (nt * 16 + lm) * 64 + kc * 32 + q * 8);
#pragma unroll
                for (int mt = 0; mt < 4; ++mt)
                    af[mt] = *(const bf16x8*)(&sA[((w + ky) * 66 + (mt * 16 + lm + kx)) * SAS + kc * 32 + q * 8]);
#pragma unroll
                for (int nt = 0; nt < 4; ++nt) {
                    if (nt * 16 < c2) {
#pragma unroll
                        for (int mt = 0; mt < 4; ++mt)
                            acc[mt][nt] = __builtin_amdgcn_mfma_f32_16x16x32_bf16(
                                af[mt], bfr[nt], acc[mt][nt], 0, 0, 0);
                    }
                }
            }
        }
    };

    __syncthreads();                           // sA ready; K-loop is barrier-free

    {
        const short* __restrict__ Wk = WB1k;
#pragma unroll 1
        for (int ky = 0; ky < 3; ++ky) {
#pragma unroll 1
            for (int kx = 0; kx < 3; ++kx) {
                compute(Wk, ky, kx);
                Wk += 4096;
            }
        }
    }

    if (TWO) {
        __syncthreads();                       // all waves done reading stage1 sA
        // restage sA center (rows 1..4, cols 1..64) with stage2 input
        for (int idx = t; idx < 4 * 64 * 8; idx += 256) {
            const int r = idx >> 9, rem = idx & 511, c = rem >> 3, sg = rem & 7;
            if (sg < SGm) {
                *(bf16x8*)(&sA[((r + 1) * 66 + (c + 1)) * SAS + sg * 8]) =
                    *(const bf16x8*)(A2 + ((n * 64 + y0 + r) * 64 + c) * 64 + sg * 8);
            }
        }
        __syncthreads();
        compute(WB2k, 1, 1);                   // conv1x1 on restaged center
    }

    // ---- epilogue ----
    const int y = y0 + w;
#pragma unroll
    for (int nt = 0; nt < 4; ++nt) {
        const int oc = nt * 16 + lm;
        float bb = bias1[oc];
        if (TWO) bb += bias2[oc];
#pragma unroll
        for (int mt = 0; mt < 4; ++mt) {
#pragma unroll
            for (int r = 0; r < 4; ++r) {
                const int xp = mt * 16 + q * 4 + r;
                const float vv = acc[mt][nt][r] + bb;   // oc>=c2: acc=0,bias=0 -> 0
                if constexpr (FINAL) {
                    const int oi = ((n * 64 + oc) * 64 + y) * 64 + xp;
                    ((float*)outp)[oi] = vv + skip[oi];
                } else {
                    ((short*)outp)[((n * 64 + y) * 64 + xp) * 64 + oc] = f2bf(fmaxf(vv, 0.f));
                }
            }
        }
    }
}

// ---------------------------------------------------------------------------
extern "C" void kernel_launch(void* const* d_in, const int* in_sizes, int n_in,
                              void* d_out, int out_size, void* d_ws, size_t ws_size,
                              hipStream_t stream) {
    (void)in_sizes; (void)n_in; (void)out_size; (void)ws_size;
    const float* x  = (const float*)d_in[0];
    const float* a1 = (const float*)d_in[1];
    const float* a2 = (const float*)d_in[2];
    const float* w3 = (const float*)d_in[3];
    const float* w1 = (const float*)d_in[4];
    const float* bn = (const float*)d_in[5];
    char* ws = (char*)d_ws;

    short* xT = (short*)(ws + OFF_XT);
    short* n1 = (short*)(ws + OFF_N1);
    short* n2 = (short*)(ws + OFF_N2);
    const short* wb3  = (const short*)(ws + OFF_WB3);
    const short* wb1  = (const short*)(ws + OFF_WB1);
    const float* bias = (const float*)(ws + OFF_BIAS);
    const int*   cc   = (const int*)(ws + OFF_CC);

    prep_kernel<<<466, 256, 0, stream>>>(w3, w1, bn, a1, a2, ws);
    transform_kernel<<<dim3(64, 32), 256, 0, stream>>>(x, xT);

    const dim3 gc(16, 32);   // y-tiles, n
    // n1 = relu(conv3(x~) e0)
    conv_kernel<false, false><<<gc, 256, 0, stream>>>(
        xT, nullptr, wb3, nullptr, bias, nullptr, cc, nullptr, n1);
    // n2 = relu(conv3(x~) e1 + conv1(n1~) e0)
    conv_kernel<true, false><<<gc, 256, 0, stream>>>(
        xT, n1, wb3 + 36864, wb1, bias + 64, bias + 128, cc, nullptr, n2);
    // d_out = x + conv3(n1~) e2 + conv1(n2~) e1
    conv_kernel<true, true><<<gc, 256, 0, stream>>>(
        n1, n2, wb3 + 2 * 36864, wb1 + 4096, bias + 192, bias + 256, cc, x, d_out);
}

// Round 5
// 139.391 us; speedup vs baseline: 5.6299x; 1.0683x over previous
//
#include <hip/hip_runtime.h>
#include <hip/hip_bf16.h>

#define DI __device__ __forceinline__

typedef __attribute__((ext_vector_type(8))) short bf16x8;   // 8 bf16 = 4 VGPRs (MFMA A/B frag)
typedef __attribute__((ext_vector_type(4))) float f32x4;    // MFMA C/D frag

constexpr int HW = 4096, CHW = 262144;

// ---- workspace layout (bytes), all 16B aligned ----
constexpr size_t OFF_XT   = 0;                       // bf16 NHWC relu(x)      16 MB
constexpr size_t OFF_N1   = 16777216;                // bf16 NHWC relu(n1)     16 MB
constexpr size_t OFF_P3   = 33554432;                // bf16 NHWC p3 = conv1_e1(n2)+b4
constexpr size_t OFF_WB3  = 50331648;                // bf16 [3][9][64oc][64ic]  (frag order)
constexpr size_t OFF_WB1  = OFF_WB3 + 221184;        // bf16 [2][64oc][64ic]
constexpr size_t OFF_BIAS = OFF_WB1 + 16384;         // f32 [5][64]
constexpr size_t OFF_CC   = OFF_BIAS + 1280;         // int[2]

DI int argmax8(const float* __restrict__ a) {
    int best = 0; float bv = a[0];
#pragma unroll
    for (int i = 1; i < 8; ++i) { float v = a[i]; if (v > bv) { bv = v; best = i; } }
    return best;
}

DI short f2bf(float v) {   // fp32 -> bf16 bits (RNE)
    __hip_bfloat16 h = __float2bfloat16(v);
    return __builtin_bit_cast(short, h);
}

// ---------------------------------------------------------------------------
// K0: transform (blocks 0..2047) + prep (blocks 2048..2559) in one launch.
// transform: x fp32 NCHW -> relu(x) bf16 NHWC via LDS transpose.
// prep: c1,c2; weights -> bf16 [edge][kpos][oc][ic], BN scale + channel masks
// folded; per-edge bias (out-masked). bn rows: 0:c3e0 1:c3e1 2:c1e0 3:c3e2 4:c1e1
// ---------------------------------------------------------------------------
__global__ __launch_bounds__(256) void prep_transform_kernel(
    const float* __restrict__ x, const float* __restrict__ w3,
    const float* __restrict__ w1, const float* __restrict__ bn,
    const float* __restrict__ a1, const float* __restrict__ a2,
    char* __restrict__ ws) {
    __shared__ short sT[64 * 72];             // [x][c], 72-pad (16B-aligned rows)
    const int t = threadIdx.x;

    if (blockIdx.x < 2048) {                  // ---- transform path ----
        short* __restrict__ xT = (short*)(ws + OFF_XT);
        const int y = blockIdx.x & 63, n = blockIdx.x >> 6;
        const int xc = t & 63, c0 = t >> 6;
        const float* __restrict__ src = x + (size_t)(n * 64) * HW + y * 64;
#pragma unroll
        for (int p = 0; p < 16; ++p) {
            const int c = p * 4 + c0;
            sT[xc * 72 + c] = f2bf(fmaxf(src[c * HW + xc], 0.f));
        }
        __syncthreads();
        short* __restrict__ dst = xT + (size_t)((n * 64 + y) * 64) * 64;
        const int cs = t & 7, xr = t >> 3;
#pragma unroll
        for (int p = 0; p < 2; ++p) {
            const int xx = p * 32 + xr;
            *(bf16x8*)(dst + xx * 64 + cs * 8) = *(const bf16x8*)(&sT[xx * 72 + cs * 8]);
        }
        return;
    }

    // ---- prep path ----
    const int c1 = 8 * (argmax8(a1) + 1);
    const int c2 = 8 * (argmax8(a2) + 1);
    short* __restrict__ wb3  = (short*)(ws + OFF_WB3);
    short* __restrict__ wb1  = (short*)(ws + OFF_WB1);
    float* __restrict__ bias = (float*)(ws + OFF_BIAS);
    int*   __restrict__ cc   = (int*)(ws + OFF_CC);

    const int idx = (blockIdx.x - 2048) * 256 + t;
    if (idx < 110592) {                       // wb3 flat = ((e*9+kp)*64+oc)*64+ic
        const int e = idx / 36864, rem = idx % 36864;
        const int kp = rem >> 12, oc = (rem >> 6) & 63, ic = rem & 63;
        const int bnrow = (e == 0) ? 0 : (e == 1) ? 1 : 3;
        const float g = bn[(bnrow * 4 + 0) * 64 + oc];
        const float v = bn[(bnrow * 4 + 3) * 64 + oc];
        const float s = g * rsqrtf(v + 1e-5f);
        const float wv = w3[((e * 64 + oc) * 64 + ic) * 9 + kp];
        wb3[idx] = (oc < c2 && ic < c1) ? f2bf(wv * s) : (short)0;
    } else if (idx < 118784) {                // wb1 flat = (e*64+oc)*64+ic
        const int j = idx - 110592;
        const int e = j >> 12, oc = (j >> 6) & 63, ic = j & 63;
        const int bnrow = (e == 0) ? 2 : 4;
        const float g = bn[(bnrow * 4 + 0) * 64 + oc];
        const float v = bn[(bnrow * 4 + 3) * 64 + oc];
        const float s = g * rsqrtf(v + 1e-5f);
        wb1[j] = (oc < c2 && ic < c1) ? f2bf(w1[(e * 64 + oc) * 64 + ic] * s) : (short)0;
    } else if (idx < 119104) {                // bias
        const int j = idx - 118784;
        const int e = j >> 6, oc = j & 63;
        const float g = bn[(e * 4 + 0) * 64 + oc];
        const float b = bn[(e * 4 + 1) * 64 + oc];
        const float m = bn[(e * 4 + 2) * 64 + oc];
        const float v = bn[(e * 4 + 3) * 64 + oc];
        bias[j] = (oc < c2) ? (b - m * g * rsqrtf(v + 1e-5f)) : 0.f;
    } else if (idx == 119104) {
        cc[0] = c1; cc[1] = c2;
    }
}

// ---------------------------------------------------------------------------
// K1: fused middle kernel. One sA staging of xT feeds BOTH conv3 edges
// (e0 -> acc1 = n1, e1 -> acc2). Then in-block chain: n1 -> LDS -> conv1_e0
// adds into acc2 (= n2); n2 -> LDS -> conv1_e1 -> p3 (bf16 NHWC). n1 also
// written globally for K2's halo read. n2 never materialized globally.
// All register-array indices compile-time (R2 spill lesson); channel culls
// are wave-uniform guards. acc3 reuses acc1's registers (disjoint liveness).
// ---------------------------------------------------------------------------
__global__ __launch_bounds__(256, 2) void fused_mid_kernel(
    const short* __restrict__ xT,      // bf16 NHWC relu(x)
    const short* __restrict__ WBe0,    // [9][64][64] conv3 e0
    const short* __restrict__ WBe1,    // [9][64][64] conv3 e1
    const short* __restrict__ W1e0,    // [64][64] conv1 e0
    const short* __restrict__ W1e1,    // [64][64] conv1 e1
    const float* __restrict__ bias,    // [5][64]
    const int* __restrict__ cc,
    short* __restrict__ n1out,         // bf16 NHWC
    short* __restrict__ p3out) {       // bf16 NHWC
    constexpr int SAS = 72;
    __shared__ __align__(16) short sA[6 * 66 * SAS];   // 55.7 KB

    const int t = threadIdx.x, w = t >> 6, l = t & 63, lm = l & 15, q = l >> 4;
    const int y0 = blockIdx.x * 4, n = blockIdx.y;
    const int c1 = __builtin_amdgcn_readfirstlane(cc[0]);
    const int c2 = __builtin_amdgcn_readfirstlane(cc[1]);
    const int SGm = (c1 > 32) ? 8 : 4;

    f32x4 acc1[4][4], acc2[4][4];
#pragma unroll
    for (int i = 0; i < 4; ++i)
#pragma unroll
        for (int j = 0; j < 4; ++j) { acc1[i][j] = 0.f; acc2[i][j] = 0.f; }

    // ---- stage sA from xT: 6 rows x 66 cols (halo) x live ic ----
    for (int idx = t; idx < 6 * 66 * 8; idx += 256) {
        const int r = idx / 528, rem = idx - r * 528, c = rem >> 3, sg = rem & 7;
        if (sg < SGm) {
            const int gy = y0 + r - 1, gx = c - 1;
            bf16x8 v = 0;
            if ((unsigned)gy < 64u && (unsigned)gx < 64u)
                v = *(const bf16x8*)(xT + ((n * 64 + gy) * 64 + gx) * 64 + sg * 8);
            *(bf16x8*)(&sA[(r * 66 + c) * SAS + sg * 8]) = v;
        }
    }
    __syncthreads();

    // ---- dual conv3 K-loop (barrier-free, sA read-only) ----
    {
        const short* __restrict__ W0 = WBe0;
        const short* __restrict__ W1 = WBe1;
#pragma unroll 1
        for (int ky = 0; ky < 3; ++ky) {
#pragma unroll 1
            for (int kx = 0; kx < 3; ++kx) {
#pragma unroll
                for (int kc = 0; kc < 2; ++kc) {
                    if (kc == 0 || c1 > 32) {
                        bf16x8 af[4], b0[4], b1[4];
#pragma unroll
                        for (int nt = 0; nt < 4; ++nt)
                            if (nt * 16 < c2) {
                                b0[nt] = *(const bf16x8*)(W0 + (nt * 16 + lm) * 64 + kc * 32 + q * 8);
                                b1[nt] = *(const bf16x8*)(W1 + (nt * 16 + lm) * 64 + kc * 32 + q * 8);
                            }
#pragma unroll
                        for (int mt = 0; mt < 4; ++mt)
                            af[mt] = *(const bf16x8*)(&sA[((w + ky) * 66 + (mt * 16 + lm + kx)) * SAS + kc * 32 + q * 8]);
#pragma unroll
                        for (int nt = 0; nt < 4; ++nt)
                            if (nt * 16 < c2) {
#pragma unroll
                                for (int mt = 0; mt < 4; ++mt) {
                                    acc1[mt][nt] = __builtin_amdgcn_mfma_f32_16x16x32_bf16(af[mt], b0[nt], acc1[mt][nt], 0, 0, 0);
                                    acc2[mt][nt] = __builtin_amdgcn_mfma_f32_16x16x32_bf16(af[mt], b1[nt], acc2[mt][nt], 0, 0, 0);
                                }
                            }
                    }
                }
                W0 += 4096; W1 += 4096;
            }
        }
    }

    __syncthreads();   // all waves done reading stage-1 sA before n1 overwrite

    // ---- epilogue 1: n1 = relu(acc1 + b0) -> global + own sA row (A-layout src) ----
    const int y = y0 + w;
#pragma unroll
    for (int nt = 0; nt < 4; ++nt) {
        const int oc = nt * 16 + lm;
        const float bv = bias[oc];
#pragma unroll
        for (int mt = 0; mt < 4; ++mt)
#pragma unroll
            for (int r = 0; r < 4; ++r) {
                const int xp = mt * 16 + q * 4 + r;
                const short s = f2bf(fmaxf(acc1[mt][nt][r] + bv, 0.f));
                n1out[((n * 64 + y) * 64 + xp) * 64 + oc] = s;
                sA[((w + 1) * 66 + xp + 1) * SAS + oc] = s;
            }
    }

    // ---- conv1_e0(n1) += acc2  (reads own sA row only; no barrier needed) ----
#pragma unroll
    for (int kc = 0; kc < 2; ++kc) {
        if (kc == 0 || c1 > 32) {
            bf16x8 af[4], bfr[4];
#pragma unroll
            for (int mt = 0; mt < 4; ++mt)
                af[mt] = *(const bf16x8*)(&sA[((w + 1) * 66 + (mt * 16 + lm + 1)) * SAS + kc * 32 + q * 8]);
#pragma unroll
            for (int nt = 0; nt < 4; ++nt)
                if (nt * 16 < c2)
                    bfr[nt] = *(const bf16x8*)(W1e0 + (nt * 16 + lm) * 64 + kc * 32 + q * 8);
#pragma unroll
            for (int nt = 0; nt < 4; ++nt)
                if (nt * 16 < c2) {
#pragma unroll
                    for (int mt = 0; mt < 4; ++mt)
                        acc2[mt][nt] = __builtin_amdgcn_mfma_f32_16x16x32_bf16(af[mt], bfr[nt], acc2[mt][nt], 0, 0, 0);
                }
        }
    }

    // ---- epilogue 2: n2 = relu(acc2 + b1 + b2) -> own sA row only ----
#pragma unroll
    for (int nt = 0; nt < 4; ++nt) {
        const int oc = nt * 16 + lm;
        const float bv = bias[64 + oc] + bias[128 + oc];
#pragma unroll
        for (int mt = 0; mt < 4; ++mt)
#pragma unroll
            for (int r = 0; r < 4; ++r) {
                const int xp = mt * 16 + q * 4 + r;
                sA[((w + 1) * 66 + xp + 1) * SAS + oc] = f2bf(fmaxf(acc2[mt][nt][r] + bv, 0.f));
            }
    }

    // ---- conv1_e1(n2) -> p3 (acc3 reuses acc1's registers) ----
    {
        f32x4 acc3[4][4];
#pragma unroll
        for (int i = 0; i < 4; ++i)
#pragma unroll
            for (int j = 0; j < 4; ++j) acc3[i][j] = 0.f;
#pragma unroll
        for (int kc = 0; kc < 2; ++kc) {
            if (kc == 0 || c1 > 32) {
                bf16x8 af[4], bfr[4];
#pragma unroll
                for (int mt = 0; mt < 4; ++mt)
                    af[mt] = *(const bf16x8*)(&sA[((w + 1) * 66 + (mt * 16 + lm + 1)) * SAS + kc * 32 + q * 8]);
#pragma unroll
                for (int nt = 0; nt < 4; ++nt)
                    if (nt * 16 < c2)
                        bfr[nt] = *(const bf16x8*)(W1e1 + (nt * 16 + lm) * 64 + kc * 32 + q * 8);
#pragma unroll
                for (int nt = 0; nt < 4; ++nt)
                    if (nt * 16 < c2) {
#pragma unroll
                        for (int mt = 0; mt < 4; ++mt)
                            acc3[mt][nt] = __builtin_amdgcn_mfma_f32_16x16x32_bf16(af[mt], bfr[nt], acc3[mt][nt], 0, 0, 0);
                    }
            }
        }
#pragma unroll
        for (int nt = 0; nt < 4; ++nt) {
            const int oc = nt * 16 + lm;
            const float bv = bias[256 + oc];
#pragma unroll
            for (int mt = 0; mt < 4; ++mt)
#pragma unroll
                for (int r = 0; r < 4; ++r) {
                    const int xp = mt * 16 + q * 4 + r;
                    p3out[((n * 64 + y) * 64 + xp) * 64 + oc] = f2bf(acc3[mt][nt][r] + bv);
                }
        }
    }
}

// ---------------------------------------------------------------------------
// K2: d_out = x + conv3_e2(n1) + p3. Single conv3 stage + fused epilogue.
// ---------------------------------------------------------------------------
__global__ __launch_bounds__(256, 2) void final_conv_kernel(
    const short* __restrict__ n1in,    // bf16 NHWC relu(n1)
    const short* __restrict__ p3in,    // bf16 NHWC (bias4 folded)
    const short* __restrict__ WBe2,    // [9][64][64] conv3 e2
    const float* __restrict__ bias3,   // [64]
    const int* __restrict__ cc,
    const float* __restrict__ skip,    // raw x fp32 NCHW
    float* __restrict__ outp) {        // fp32 NCHW
    constexpr int SAS = 72;
    __shared__ __align__(16) short sA[6 * 66 * SAS];

    const int t = threadIdx.x, w = t >> 6, l = t & 63, lm = l & 15, q = l >> 4;
    const int y0 = blockIdx.x * 4, n = blockIdx.y;
    const int c1 = __builtin_amdgcn_readfirstlane(cc[0]);
    const int c2 = __builtin_amdgcn_readfirstlane(cc[1]);
    const int SGm = (c1 > 32) ? 8 : 4;

    f32x4 acc[4][4];
#pragma unroll
    for (int i = 0; i < 4; ++i)
#pragma unroll
        for (int j = 0; j < 4; ++j) acc[i][j] = 0.f;

    for (int idx = t; idx < 6 * 66 * 8; idx += 256) {
        const int r = idx / 528, rem = idx - r * 528, c = rem >> 3, sg = rem & 7;
        if (sg < SGm) {
            const int gy = y0 + r - 1, gx = c - 1;
            bf16x8 v = 0;
            if ((unsigned)gy < 64u && (unsigned)gx < 64u)
                v = *(const bf16x8*)(n1in + ((n * 64 + gy) * 64 + gx) * 64 + sg * 8);
            *(bf16x8*)(&sA[(r * 66 + c) * SAS + sg * 8]) = v;
        }
    }
    __syncthreads();

    {
        const short* __restrict__ Wk = WBe2;
#pragma unroll 1
        for (int ky = 0; ky < 3; ++ky) {
#pragma unroll 1
            for (int kx = 0; kx < 3; ++kx) {
#pragma unroll
                for (int kc = 0; kc < 2; ++kc) {
                    if (kc == 0 || c1 > 32) {
                        bf16x8 af[4], bfr[4];
#pragma unroll
                        for (int nt = 0; nt < 4; ++nt)
                            if (nt * 16 < c2)
                                bfr[nt] = *(const bf16x8*)(Wk + (nt * 16 + lm) * 64 + kc * 32 + q * 8);
#pragma unroll
                        for (int mt = 0; mt < 4; ++mt)
                            af[mt] = *(const bf16x8*)(&sA[((w + ky) * 66 + (mt * 16 + lm + kx)) * SAS + kc * 32 + q * 8]);
#pragma unroll
                        for (int nt = 0; nt < 4; ++nt)
                            if (nt * 16 < c2) {
#pragma unroll
                                for (int mt = 0; mt < 4; ++mt)
                                    acc[mt][nt] = __builtin_amdgcn_mfma_f32_16x16x32_bf16(af[mt], bfr[nt], acc[mt][nt], 0, 0, 0);
                            }
                    }
                }
                Wk += 4096;
            }
        }
    }

    const int y = y0 + w;
#pragma unroll
    for (int nt = 0; nt < 4; ++nt) {
        const int oc = nt * 16 + lm;
        const float bv = bias3[oc];
#pragma unroll
        for (int mt = 0; mt < 4; ++mt)
#pragma unroll
            for (int r = 0; r < 4; ++r) {
                const int xp = mt * 16 + q * 4 + r;
                const float p3v = __bfloat162float(
                    ((const __hip_bfloat16*)p3in)[((n * 64 + y) * 64 + xp) * 64 + oc]);
                const int oi = ((n * 64 + oc) * 64 + y) * 64 + xp;
                outp[oi] = skip[oi] + acc[mt][nt][r] + bv + p3v;   // oc>=c2: acc=bv=p3=0
            }
    }
}

// ---------------------------------------------------------------------------
extern "C" void kernel_launch(void* const* d_in, const int* in_sizes, int n_in,
                              void* d_out, int out_size, void* d_ws, size_t ws_size,
                              hipStream_t stream) {
    (void)in_sizes; (void)n_in; (void)out_size; (void)ws_size;
    const float* x  = (const float*)d_in[0];
    const float* a1 = (const float*)d_in[1];
    const float* a2 = (const float*)d_in[2];
    const float* w3 = (const float*)d_in[3];
    const float* w1 = (const float*)d_in[4];
    const float* bn = (const float*)d_in[5];
    char* ws = (char*)d_ws;

    short* xT = (short*)(ws + OFF_XT);
    short* n1 = (short*)(ws + OFF_N1);
    short* p3 = (short*)(ws + OFF_P3);
    const short* wb3  = (const short*)(ws + OFF_WB3);
    const short* wb1  = (const short*)(ws + OFF_WB1);
    const float* bias = (const float*)(ws + OFF_BIAS);
    const int*   cc   = (const int*)(ws + OFF_CC);

    prep_transform_kernel<<<2560, 256, 0, stream>>>(x, w3, w1, bn, a1, a2, ws);

    const dim3 gc(16, 32);   // y-tiles, n
    fused_mid_kernel<<<gc, 256, 0, stream>>>(
        xT, wb3, wb3 + 36864, wb1, wb1 + 4096, bias, cc, n1, p3);
    final_conv_kernel<<<gc, 256, 0, stream>>>(
        n1, p3, wb3 + 2 * 36864, bias + 192, cc, x, (float*)d_out);
}